// Round 1
// 195.324 us; speedup vs baseline: 1.0146x; 1.0146x over previous
//
#include <hip/hip_runtime.h>
#include <hip/hip_bf16.h>
#include <stdint.h>

typedef __attribute__((ext_vector_type(8))) short bf16x8;
typedef __attribute__((ext_vector_type(4))) float f32x4;

#define MFMA16(a, b, c) __builtin_amdgcn_mfma_f32_16x16x32_bf16((a), (b), (c), 0, 0, 0)

__device__ __forceinline__ unsigned short f2bf(float f) {
  unsigned int u = __builtin_bit_cast(unsigned int, f);
  unsigned int r = (u + 0x7fffu + ((u >> 16) & 1u)) >> 16;
  return (unsigned short)r;
}

__device__ __forceinline__ void gload16(const unsigned short* g, unsigned short* lds_dst) {
  __builtin_amdgcn_global_load_lds(
      (const __attribute__((address_space(1))) unsigned int*)g,
      (__attribute__((address_space(3))) unsigned int*)lds_dst, 16, 0, 0);
}

// ---------------- f32 -> bf16 conversion ----------------
__global__ void cvt_f32_bf16(const float* __restrict__ in, unsigned short* __restrict__ out, long n) {
  long i = ((long)blockIdx.x * blockDim.x + threadIdx.x) * 4;
  long stride = (long)gridDim.x * blockDim.x * 4;
  for (; i < n; i += stride) {
    float4 v = *(const float4*)(in + i);
    ushort4 o;
    o.x = f2bf(v.x); o.y = f2bf(v.y); o.z = f2bf(v.z); o.w = f2bf(v.w);
    *(ushort4*)(out + i) = o;
  }
}

// ---------------- 128x256 B^T GEMM, 4-phase pipelined (T3+T4+T2+T5) ----------------
// 512 threads = 8 waves (2M x 4N), per-wave 64x64 output, BK=64 (2 k-steps).
// Triple-buffered LDS (144 KB), prefetch distance 2 K-tiles, counted vmcnt(6)
// (never drained to 0 in the main loop). LDS rows are 64 bf16 = 128B; frag
// reads use granule XOR swizzle (g ^= row&7) with inverse-swizzled global
// source on the gload_lds side (linear dest), same involution as the attn STAGE.
// K is assumed == 1024 (16 K-tiles), M % 128 == 0, N % 256 == 0.
template <int EPI>
__global__ __launch_bounds__(512, 2)
void gemm_bt(const unsigned short* __restrict__ A,
             const unsigned short* __restrict__ Bt,
             const float* __restrict__ bias,
             int M, int N, int K,
             unsigned short* __restrict__ q_out,
             unsigned short* __restrict__ k_out,
             unsigned short* __restrict__ vt_out,
             float* __restrict__ f_out) {
  alignas(16) __shared__ unsigned short Ash[3][128 * 64];   // 3 x 16 KB
  alignas(16) __shared__ unsigned short Bsh[3][256 * 64];   // 3 x 32 KB
  const int t = threadIdx.x, w = t >> 6, l = t & 63;
  const int bm = blockIdx.x, bn = blockIdx.y;
  const int wm = w >> 2, wn = w & 3;          // wave grid 2(M) x 4(N)
  const int lo = l & 15, hi = l >> 4, swk = l & 7;

  f32x4 acc[4][4];
  const f32x4 zero = {0.f, 0.f, 0.f, 0.f};
#pragma unroll
  for (int i = 0; i < 4; ++i)
#pragma unroll
    for (int j = 0; j < 4; ++j) acc[i][j] = zero;

  // ---- staging geometry: thread t writes granule (l&7) of LDS row (call_base + (l>>3)).
  // A-tile rows: call c covers rows w*16 + c*8 .. +8 ; B-tile: w*32 + c*8 .. +8.
  // Source granule is inverse-swizzled: g_src = (l&7) ^ (row&7); row&7 == l>>3 for all calls.
  const int lr = l >> 3;
  const int gsrc = ((l & 7) ^ lr) * 8;   // element offset within the 64-el row
  const int rA0 = w * 16 + lr,     rA1 = w * 16 + 8 + lr;
  const int rB0 = w * 32 + lr,     rB1 = w * 32 + 8 + lr;
  const int rB2 = w * 32 + 16 + lr, rB3 = w * 32 + 24 + lr;
  const unsigned short* sA0 = A + (long)(bm * 128 + rA0) * K + gsrc;
  const unsigned short* sA1 = A + (long)(bm * 128 + rA1) * K + gsrc;
  const unsigned short* sB0 = Bt + (long)(bn * 256 + rB0) * K + gsrc;
  const unsigned short* sB1 = Bt + (long)(bn * 256 + rB1) * K + gsrc;
  const unsigned short* sB2 = Bt + (long)(bn * 256 + rB2) * K + gsrc;
  const unsigned short* sB3 = Bt + (long)(bn * 256 + rB3) * K + gsrc;

#define STAGE_A(off, sb) do { unsigned short* d_ = &Ash[sb][w * 1024];        \
    gload16(sA0 + (off), d_); gload16(sA1 + (off), d_ + 512); } while (0)
#define STAGE_B01(off, sb) do { unsigned short* d_ = &Bsh[sb][w * 2048];      \
    gload16(sB0 + (off), d_); gload16(sB1 + (off), d_ + 512); } while (0)
#define STAGE_B23(off, sb) do { unsigned short* d_ = &Bsh[sb][w * 2048];      \
    gload16(sB2 + (off), d_ + 1024); gload16(sB3 + (off), d_ + 1536); } while (0)

  // ---- prologue: stage tiles 0 and 1 (6 loads each, tile-ordered for vmcnt)
  STAGE_A(0, 0);  STAGE_B01(0, 0);  STAGE_B23(0, 0);
  STAGE_A(64, 1); STAGE_B01(64, 1); STAGE_B23(64, 1);
  asm volatile("s_waitcnt vmcnt(6)" ::: "memory");   // tile 0 landed
  __builtin_amdgcn_sched_barrier(0);
  __builtin_amdgcn_s_barrier();

  // ---- frag read geometry (swizzled): row keys are lo&7 == swk for all frags
  const int ra = wm * 64 + lo;          // + m*16
  const int rb = wn * 64 + lo;          // + n*16
  const int g0 = (hi ^ swk) * 8;        // k-step 0 granule
  const int g1 = ((4 + hi) ^ swk) * 8;  // k-step 1 granule

  int cb = 0;        // compute buffer = kt % 3
  int koff = 128;    // element k-offset of tile kt+2
  for (int kt = 0; kt < 16; ++kt) {
    const unsigned short* As = Ash[cb];
    const unsigned short* Bs = Bsh[cb];
    int sb = cb + 2; if (sb >= 3) sb -= 3;   // (kt+2) % 3
    const bool st = (kt < 14);

    // ======== P1: read A m0,m1 + B n0,n1 ; stage A(kt+2) ; MFMA (m01 x n01)
    bf16x8 a00 = *(const bf16x8*)&As[(ra)*64 + g0];
    bf16x8 a01 = *(const bf16x8*)&As[(ra)*64 + g1];
    bf16x8 a10 = *(const bf16x8*)&As[(ra + 16) * 64 + g0];
    bf16x8 a11 = *(const bf16x8*)&As[(ra + 16) * 64 + g1];
    bf16x8 b00 = *(const bf16x8*)&Bs[(rb)*64 + g0];
    bf16x8 b01 = *(const bf16x8*)&Bs[(rb)*64 + g1];
    bf16x8 b10 = *(const bf16x8*)&Bs[(rb + 16) * 64 + g0];
    bf16x8 b11 = *(const bf16x8*)&Bs[(rb + 16) * 64 + g1];
    if (st) STAGE_A(koff, sb);
    __builtin_amdgcn_s_barrier();
    asm volatile("s_waitcnt lgkmcnt(0)" ::: "memory");
    __builtin_amdgcn_sched_barrier(0);
    __builtin_amdgcn_s_setprio(1);
    acc[0][0] = MFMA16(a00, b00, acc[0][0]);
    acc[0][1] = MFMA16(a00, b10, acc[0][1]);
    acc[1][0] = MFMA16(a10, b00, acc[1][0]);
    acc[1][1] = MFMA16(a10, b10, acc[1][1]);
    acc[0][0] = MFMA16(a01, b01, acc[0][0]);
    acc[0][1] = MFMA16(a01, b11, acc[0][1]);
    acc[1][0] = MFMA16(a11, b01, acc[1][0]);
    acc[1][1] = MFMA16(a11, b11, acc[1][1]);
    __builtin_amdgcn_s_setprio(0);
    __builtin_amdgcn_sched_barrier(0);
    __builtin_amdgcn_s_barrier();

    // ======== P2: read B n2,n3 ; stage B01(kt+2) ; MFMA (m01 x n23)
    bf16x8 b20 = *(const bf16x8*)&Bs[(rb + 32) * 64 + g0];
    bf16x8 b21 = *(const bf16x8*)&Bs[(rb + 32) * 64 + g1];
    bf16x8 b30 = *(const bf16x8*)&Bs[(rb + 48) * 64 + g0];
    bf16x8 b31 = *(const bf16x8*)&Bs[(rb + 48) * 64 + g1];
    if (st) STAGE_B01(koff, sb);
    __builtin_amdgcn_s_barrier();
    asm volatile("s_waitcnt lgkmcnt(0)" ::: "memory");
    __builtin_amdgcn_sched_barrier(0);
    __builtin_amdgcn_s_setprio(1);
    acc[0][2] = MFMA16(a00, b20, acc[0][2]);
    acc[0][3] = MFMA16(a00, b30, acc[0][3]);
    acc[1][2] = MFMA16(a10, b20, acc[1][2]);
    acc[1][3] = MFMA16(a10, b30, acc[1][3]);
    acc[0][2] = MFMA16(a01, b21, acc[0][2]);
    acc[0][3] = MFMA16(a01, b31, acc[0][3]);
    acc[1][2] = MFMA16(a11, b21, acc[1][2]);
    acc[1][3] = MFMA16(a11, b31, acc[1][3]);
    __builtin_amdgcn_s_setprio(0);
    __builtin_amdgcn_sched_barrier(0);
    __builtin_amdgcn_s_barrier();

    // ======== P3: read A m2,m3 ; stage B23(kt+2) ; MFMA (m23 x n23)
    bf16x8 a20 = *(const bf16x8*)&As[(ra + 32) * 64 + g0];
    bf16x8 a21 = *(const bf16x8*)&As[(ra + 32) * 64 + g1];
    bf16x8 a30 = *(const bf16x8*)&As[(ra + 48) * 64 + g0];
    bf16x8 a31 = *(const bf16x8*)&As[(ra + 48) * 64 + g1];
    if (st) STAGE_B23(koff, sb);
    __builtin_amdgcn_s_barrier();
    asm volatile("s_waitcnt lgkmcnt(0)" ::: "memory");
    __builtin_amdgcn_sched_barrier(0);
    __builtin_amdgcn_s_setprio(1);
    acc[2][2] = MFMA16(a20, b20, acc[2][2]);
    acc[2][3] = MFMA16(a20, b30, acc[2][3]);
    acc[3][2] = MFMA16(a30, b20, acc[3][2]);
    acc[3][3] = MFMA16(a30, b30, acc[3][3]);
    acc[2][2] = MFMA16(a21, b21, acc[2][2]);
    acc[2][3] = MFMA16(a21, b31, acc[2][3]);
    acc[3][2] = MFMA16(a31, b21, acc[3][2]);
    acc[3][3] = MFMA16(a31, b31, acc[3][3]);
    __builtin_amdgcn_s_setprio(0);
    __builtin_amdgcn_sched_barrier(0);
    __builtin_amdgcn_s_barrier();

    // ======== P4: no reads (reuse a2x + b0x/b1x) ; MFMA (m23 x n01) ; counted vmcnt
    __builtin_amdgcn_s_setprio(1);
    acc[2][0] = MFMA16(a20, b00, acc[2][0]);
    acc[2][1] = MFMA16(a20, b10, acc[2][1]);
    acc[3][0] = MFMA16(a30, b00, acc[3][0]);
    acc[3][1] = MFMA16(a30, b10, acc[3][1]);
    acc[2][0] = MFMA16(a21, b01, acc[2][0]);
    acc[2][1] = MFMA16(a21, b11, acc[2][1]);
    acc[3][0] = MFMA16(a31, b01, acc[3][0]);
    acc[3][1] = MFMA16(a31, b11, acc[3][1]);
    __builtin_amdgcn_s_setprio(0);
    if (kt < 14) {
      asm volatile("s_waitcnt vmcnt(6)" ::: "memory");   // tile kt+1 landed; kt+2 in flight
    } else if (kt == 14) {
      asm volatile("s_waitcnt vmcnt(0)" ::: "memory");   // drain last tile
    }
    __builtin_amdgcn_sched_barrier(0);
    __builtin_amdgcn_s_barrier();

    cb += 1; if (cb == 3) cb = 0;
    koff += 64;
  }
#undef STAGE_A
#undef STAGE_B01
#undef STAGE_B23

  // ---- epilogue ----
#pragma unroll
  for (int i = 0; i < 4; ++i) {
#pragma unroll
    for (int j = 0; j < 4; ++j) {
#pragma unroll
      for (int r = 0; r < 4; ++r) {
        int row = bm * 128 + wm * 64 + i * 16 + hi * 4 + r;
        int col = bn * 256 + wn * 64 + j * 16 + lo;
        float v = acc[i][j][r] + bias[col];
        if (EPI == 0) {
          int b = row >> 11, tt = row & 2047;
          int seg = col >> 10, cc = col & 1023;
          int h = cc >> 6, d = cc & 63;
          long bh = (long)(b * 16 + h);
          // Q pre-scaled by 1/sqrt(64) * log2(e) (softmax runs in exp2 domain)
          if (seg == 0)      q_out[(bh * 2048 + tt) * 64 + d] = f2bf(v * 0.1803368801111f);
          else if (seg == 1) k_out[(bh * 2048 + tt) * 64 + d] = f2bf(v);
          else               vt_out[(bh * 64 + d) * 2048 + tt] = f2bf(v);
        } else {
          f_out[(long)row * N + col] = v;
        }
      }
    }
  }
}

// ---------------- causal flash attention v5 (unchanged) ----------------
__global__ __launch_bounds__(512, 4)
void attn_kernel(const unsigned short* __restrict__ Q,
                 const unsigned short* __restrict__ K,
                 const unsigned short* __restrict__ Vt,
                 unsigned short* __restrict__ Y) {
  alignas(16) __shared__ unsigned short Kbuf[2][64 * 64];
  alignas(16) __shared__ unsigned short Vbuf[2][64 * 64];
  alignas(16) __shared__ unsigned short pbuf[8][16 * 64];
  const int t = threadIdx.x, w = t >> 6, l = t & 63;
  const int lo = l & 15, hi = l >> 4;
  const int bh = blockIdx.x;
  const int p = blockIdx.y;
  const int b = bh >> 4, h = bh & 15;
  const int sA = p, sB = 15 - p;
  const int nA = 2 * p + 2;
  const int nTot = 34;
  const unsigned short* Qp = Q + (long)bh * 2048 * 64;
  const unsigned short* Kp = K + (long)bh * 2048 * 64;
  const unsigned short* Vp = Vt + (long)bh * 64 * 2048;
  unsigned short* pw = pbuf[w];

  const short one_bf = (short)0x3F80;
  const bf16x8 ones = {one_bf, one_bf, one_bf, one_bf, one_bf, one_bf, one_bf, one_bf};
  const f32x4 zero = {0.f, 0.f, 0.f, 0.f};

  const int qbA = sA * 128 + w * 16;
  const int qbB = sB * 128 + w * 16;

  bf16x8 qf0, qf1;
  float mcol;
  f32x4 lsum;
  f32x4 oacc[4];

  qf0 = *(const bf16x8*)&Qp[(qbA + lo) * 64 + hi * 8];
  qf1 = *(const bf16x8*)&Qp[(qbA + lo) * 64 + 32 + hi * 8];
  mcol = -__builtin_inff();
  lsum = zero;
#pragma unroll
  for (int dg = 0; dg < 4; ++dg) oacc[dg] = zero;

  const int srow = t >> 3;
  const int scw = ((t & 7) ^ (srow & 7)) * 8;
  const int sw = lo & 7;

#define STAGE(kvoff, bufidx)                                          \
  do {                                                                \
    unsigned short* KB_ = Kbuf[bufidx] + w * 512;                     \
    unsigned short* VB_ = Vbuf[bufidx] + w * 512;                     \
    gload16(Kp + (long)((kvoff) + srow) * 64 + scw, KB_);             \
    gload16(Vp + (long)srow * 2048 + (kvoff) + scw, VB_);             \
  } while (0)

  STAGE(0, 0);
  __syncthreads();

  for (int g = 0; g < nTot; ++g) {
    const bool inA = (g < nA);
    const int kvb = (inA ? g : g - nA) * 64;
    const int cur = g & 1;
    if (g + 1 < nTot) {
      const int jn = (g + 1 < nA) ? g + 1 : g + 1 - nA;
      STAGE(jn * 64, cur ^ 1);
    }
    const int qbase = inA ? qbA : qbB;
    if (kvb <= qbase + 15) {
      const unsigned short* KB = Kbuf[cur];
      const unsigned short* VB = Vbuf[cur];
      f32x4 s[4];
#pragma unroll
      for (int cg = 0; cg < 4; ++cg) s[cg] = zero;
      __builtin_amdgcn_s_setprio(1);
#pragma unroll
      for (int cg = 0; cg < 4; ++cg) {
        bf16x8 k0 = *(const bf16x8*)&KB[(cg * 16 + lo) * 64 + ((hi) ^ sw) * 8];
        bf16x8 k1 = *(const bf16x8*)&KB[(cg * 16 + lo) * 64 + ((4 + hi) ^ sw) * 8];
        s[cg] = MFMA16(k0, qf0, s[cg]);
        s[cg] = MFMA16(k1, qf1, s[cg]);
      }
      __builtin_amdgcn_s_setprio(0);
      if (kvb + 63 > qbase) {
        const int limit = qbase + lo - kvb;
#pragma unroll
        for (int cg = 0; cg < 4; ++cg)
#pragma unroll
          for (int r = 0; r < 4; ++r)
            if (cg * 16 + hi * 4 + r > limit) s[cg][r] = -__builtin_inff();
      }
      float pm = fmaxf(fmaxf(fmaxf(s[0][0], s[0][1]), fmaxf(s[0][2], s[0][3])),
                       fmaxf(fmaxf(s[1][0], s[1][1]), fmaxf(s[1][2], s[1][3])));
      pm = fmaxf(pm, fmaxf(fmaxf(fmaxf(s[2][0], s[2][1]), fmaxf(s[2][2], s[2][3])),
                           fmaxf(fmaxf(s[3][0], s[3][1]), fmaxf(s[3][2], s[3][3]))));
      pm = fmaxf(pm, __shfl_xor(pm, 16));
      pm = fmaxf(pm, __shfl_xor(pm, 32));
      float mn;
      if (__all(pm <= mcol + 11.54f)) {
        mn = mcol;
      } else {
        mn = fmaxf(mcol, pm);
        float a = exp2f(mcol - mn);
        mcol = mn;
        float ar[4];
#pragma unroll
        for (int r = 0; r < 4; ++r) ar[r] = __shfl(a, hi * 4 + r);
#pragma unroll
        for (int r = 0; r < 4; ++r) {
          lsum[r] *= ar[r];
#pragma unroll
          for (int dg = 0; dg < 4; ++dg) oacc[dg][r] *= ar[r];
        }
      }
#pragma unroll
      for (int cg = 0; cg < 4; ++cg) {
        float p0 = exp2f(s[cg][0] - mn);
        float p1 = exp2f(s[cg][1] - mn);
        float p2 = exp2f(s[cg][2] - mn);
        float p3 = exp2f(s[cg][3] - mn);
        unsigned int u0, u1;
        asm("v_cvt_pk_bf16_f32 %0, %1, %2" : "=v"(u0) : "v"(p0), "v"(p1));
        asm("v_cvt_pk_bf16_f32 %0, %1, %2" : "=v"(u1) : "v"(p2), "v"(p3));
        const int gg = (cg * 2 + (hi >> 1)) ^ sw;
        uint2 val; val.x = u0; val.y = u1;
        *(uint2*)&pw[lo * 64 + gg * 8 + (hi & 1) * 4] = val;
      }
      asm volatile("s_waitcnt lgkmcnt(0)" ::: "memory");
      bf16x8 pa0 = *(const bf16x8*)&pw[lo * 64 + ((hi) ^ sw) * 8];
      bf16x8 pa1 = *(const bf16x8*)&pw[lo * 64 + ((4 + hi) ^ sw) * 8];
      __builtin_amdgcn_s_setprio(1);
      lsum = MFMA16(pa0, ones, lsum);
      lsum = MFMA16(pa1, ones, lsum);
#pragma unroll
      for (int dg = 0; dg < 4; ++dg) {
        bf16x8 vv0 = *(const bf16x8*)&VB[(dg * 16 + lo) * 64 + ((hi) ^ sw) * 8];
        bf16x8 vv1 = *(const bf16x8*)&VB[(dg * 16 + lo) * 64 + ((4 + hi) ^ sw) * 8];
        oacc[dg] = MFMA16(pa0, vv0, oacc[dg]);
        oacc[dg] = MFMA16(pa1, vv1, oacc[dg]);
      }
      __builtin_amdgcn_s_setprio(0);
    }
    if (g == nA - 1) {
#pragma unroll
      for (int r = 0; r < 4; ++r) {
        float inv = 1.0f / lsum[r];
        int rowg = qbA + hi * 4 + r;
        long base = ((long)b * 2048 + rowg) * 1024 + h * 64;
#pragma unroll
        for (int dg = 0; dg < 4; ++dg)
          Y[base + dg * 16 + lo] = f2bf(oacc[dg][r] * inv);
      }
      qf0 = *(const bf16x8*)&Qp[(qbB + lo) * 64 + hi * 8];
      qf1 = *(const bf16x8*)&Qp[(qbB + lo) * 64 + 32 + hi * 8];
      mcol = -__builtin_inff();
      lsum = zero;
#pragma unroll
      for (int dg = 0; dg < 4; ++dg) oacc[dg] = zero;
    }
    __syncthreads();
  }

#pragma unroll
  for (int r = 0; r < 4; ++r) {
    float inv = 1.0f / lsum[r];
    int rowg = qbB + hi * 4 + r;
    long base = ((long)b * 2048 + rowg) * 1024 + h * 64;
#pragma unroll
    for (int dg = 0; dg < 4; ++dg)
      Y[base + dg * 16 + lo] = f2bf(oacc[dg][r] * inv);
  }
#undef STAGE
}

extern "C" void kernel_launch(void* const* d_in, const int* in_sizes, int n_in,
                              void* d_out, int out_size, void* d_ws, size_t ws_size,
                              hipStream_t stream) {
  const float* x      = (const float*)d_in[0];
  const float* w_attn = (const float*)d_in[1];
  const float* b_attn = (const float*)d_in[2];
  const float* w_proj = (const float*)d_in[3];
  const float* b_proj = (const float*)d_in[4];
  float* out = (float*)d_out;

  const long NX = 8192L * 1024;
  const long NWA = 3072L * 1024;
  const long NWP = 1024L * 1024;
  const long NQ = 64L * 2048 * 64;

  char* ws = (char*)d_ws;
  unsigned short* xb  = (unsigned short*)ws; ws += NX * 2;
  unsigned short* wab = (unsigned short*)ws; ws += NWA * 2;
  unsigned short* wpb = (unsigned short*)ws; ws += NWP * 2;
  unsigned short* qb  = (unsigned short*)ws; ws += NQ * 2;
  unsigned short* kb  = (unsigned short*)ws; ws += NQ * 2;
  unsigned short* vtb = (unsigned short*)ws; ws += NQ * 2;
  unsigned short* yb  = (unsigned short*)ws; ws += NX * 2;

  cvt_f32_bf16<<<2048, 256, 0, stream>>>(x, xb, NX);
  cvt_f32_bf16<<<768, 256, 0, stream>>>(w_attn, wab, NWA);
  cvt_f32_bf16<<<256, 256, 0, stream>>>(w_proj, wpb, NWP);

  dim3 g1(64, 12);
  gemm_bt<0><<<g1, 512, 0, stream>>>(xb, wab, b_attn, 8192, 3072, 1024,
                                     qb, kb, vtb, nullptr);
  dim3 ga(64, 8);
  attn_kernel<<<ga, 512, 0, stream>>>(qb, kb, vtb, yb);
  dim3 g2(64, 4);
  gemm_bt<1><<<g2, 512, 0, stream>>>(yb, wpb, b_proj, 8192, 1024, 1024,
                                     nullptr, nullptr, nullptr, out);
}